// Round 17
// baseline (265.637 us; speedup 1.0000x reference)
//
#include <hip/hip_runtime.h>
#include <cstdint>

#define CD 64
#define HWD 589824
#define K1_BLOCKS 768
#define TPB 6                        // 128-col tiles per block (768-col span)
#define K1_ROWS (K1_BLOCKS * 4)      // 3072 cell rows (one per wave)
#define STRIP 48                     // cell rows per k2 block
#define FMAXV 3.402823466e+38f

typedef float f32x16 __attribute__((ext_vector_type(16)));
typedef short bf16x8 __attribute__((ext_vector_type(8)));

__device__ __forceinline__ short f2bf(float f) {
    unsigned u = __float_as_uint(f);
    u = u + 0x7FFFu + ((u >> 16) & 1u);   // RNE
    return (short)(u >> 16);
}

// sorted top-4 insert: t.x <= t.y <= t.z <= t.w
__device__ __forceinline__ void ins4(float4& t, float x) {
    if (x < t.w) {
        if (x < t.z) { t.w = t.z;
            if (x < t.y) { t.z = t.y;
                if (x < t.x) { t.y = t.x; t.x = x; } else t.y = x;
            } else t.z = x;
        } else t.w = x;
    }
}

// unsorted 8-smallest screen (static indexing)
#define SCREEN8(d, lst, cm)                                                 \
    if ((d) < (cm)) {                                                       \
        bool rep = false;                                                   \
        _Pragma("unroll")                                                   \
        for (int j = 0; j < 8; ++j)                                         \
            if (!rep && lst[j] == (cm)) { lst[j] = (d); rep = true; }       \
        cm = lst[0];                                                        \
        _Pragma("unroll")                                                   \
        for (int j = 1; j < 8; ++j) cm = fmaxf(cm, lst[j]);                 \
    }

// unsorted 16-smallest screen (static indexing)
#define SCREEN16(d, lst, cm)                                                \
    if ((d) < (cm)) {                                                       \
        bool rep = false;                                                   \
        _Pragma("unroll")                                                   \
        for (int j = 0; j < 16; ++j)                                        \
            if (!rep && lst[j] == (cm)) { lst[j] = (d); rep = true; }       \
        cm = lst[0];                                                        \
        _Pragma("unroll")                                                   \
        for (int j = 1; j < 16; ++j) cm = fmaxf(cm, lst[j]);                \
    }

#define CSW(a, b) { float _mn = fminf(a, b), _mx = fmaxf(a, b); a = _mn; b = _mx; }

// k1: 768 blocks (3/CU, single residency round) x 256 thr.
// Phase 0: inline sel gather -> LDS -> bf16 frags + ||sel||^2 (R8 pattern).
// Then R14 reg-staged async pipeline over 6x128-col tiles: issue next tile's
// 8 float4 loads -> compute current from LDS via MFMA -> top-4 per p.
__global__ __launch_bounds__(256) void k1_topk(
    const float* __restrict__ f1, const float* __restrict__ f2,
    const int* __restrict__ nidx, float4* __restrict__ cells,
    unsigned* __restrict__ ticket)
{
    __shared__ float lds[CD][128];    // 32 KB
    __shared__ float selk[CD][65];    // 16.25 KB (padded)
    __shared__ float sel2s[CD];
    const int tid = threadIdx.x;
    const int lane = tid & 63, wid = tid >> 6;
    const int l31 = lane & 31, lh = lane >> 5;

    if (blockIdx.x == 0 && tid == 0) *ticket = 0u;   // reset before k2 runs

    // phase 0: sel gather (4096 scattered loads, L3-hot after first blocks)
#pragma unroll
    for (int q = 0; q < 16; ++q) {
        int idx = q * 256 + tid;
        int p = idx >> 6, k = idx & 63;
        selk[p][k] = f1[(long)k * HWD + nidx[p]];
    }
    __syncthreads();
    if (tid < CD) {
        float s = 0.f;
#pragma unroll
        for (int k = 0; k < CD; ++k) s += selk[tid][k] * selk[tid][k];
        sel2s[tid] = s;
    }
    __syncthreads();

    bf16x8 sf0[4], sf1[4];
#pragma unroll
    for (int ks = 0; ks < 4; ++ks) {
#pragma unroll
        for (int j = 0; j < 8; ++j) {
            sf0[ks][j] = f2bf(selk[l31][16 * ks + 8 * lh + j]);
            sf1[ks][j] = f2bf(selk[l31 + 32][16 * ks + 8 * lh + j]);
        }
    }
    const float sel20 = sel2s[l31], sel21 = sel2s[l31 + 32];

    const long nb = (long)blockIdx.x * (TPB * 128);
    const int srow = tid >> 5;          // 0..7
    const int scol = (tid & 31) * 4;    // float4 column

    float4 st[8];
#pragma unroll
    for (int i = 0; i < 8; ++i)
        st[i] = *(const float4*)(f2 + (long)(8 * i + srow) * HWD + nb + scol);
    __builtin_amdgcn_sched_barrier(0);
#pragma unroll
    for (int i = 0; i < 8; ++i)
        *(float4*)&lds[8 * i + srow][scol] = st[i];

    float4 t = make_float4(FMAXV, FMAXV, FMAXV, FMAXV);
    float4 u = t;

#pragma unroll
    for (int tt = 0; tt < TPB; ++tt) {
        if (tt + 1 < TPB) {
#pragma unroll
            for (int i = 0; i < 8; ++i)
                st[i] = *(const float4*)(f2 + (long)(8 * i + srow) * HWD
                                         + nb + (long)(tt + 1) * 128 + scol);
            __builtin_amdgcn_sched_barrier(0);
        }
        asm volatile("s_waitcnt lgkmcnt(0)" ::: "memory");
        __builtin_amdgcn_sched_barrier(0);
        __builtin_amdgcn_s_barrier();
        __builtin_amdgcn_sched_barrier(0);

        const int col = wid * 32 + l31;
        float fs = 0.f;
        f32x16 a0, a1;
#pragma unroll
        for (int i = 0; i < 16; ++i) { a0[i] = 0.f; a1[i] = 0.f; }
#pragma unroll
        for (int ks = 0; ks < 4; ++ks) {
            bf16x8 af;
#pragma unroll
            for (int j = 0; j < 8; ++j) {
                float v = lds[16 * ks + 8 * lh + j][col];
                fs += v * v;
                af[j] = f2bf(v);
            }
            a0 = __builtin_amdgcn_mfma_f32_32x32x16_bf16(af, sf0[ks], a0, 0, 0, 0);
            a1 = __builtin_amdgcn_mfma_f32_32x32x16_bf16(af, sf1[ks], a1, 0, 0, 0);
        }
        fs += __shfl_xor(fs, 32);       // combine k-halves (same col)

#pragma unroll
        for (int i = 0; i < 16; ++i) {
            int r = (i & 3) + 8 * (i >> 2) + 4 * lh;
            float fr2 = __shfl(fs, r);
            ins4(t, fmaxf(sel20 + fr2 - 2.f * a0[i], 0.f));   // p = l31
            ins4(u, fmaxf(sel21 + fr2 - 2.f * a1[i], 0.f));   // p = l31+32
        }

        asm volatile("s_waitcnt lgkmcnt(0)" ::: "memory");
        __builtin_amdgcn_sched_barrier(0);
        __builtin_amdgcn_s_barrier();
        __builtin_amdgcn_sched_barrier(0);

        if (tt + 1 < TPB) {
#pragma unroll
            for (int i = 0; i < 8; ++i)
                *(float4*)&lds[8 * i + srow][scol] = st[i];
        }
    }

    {   // merge lh halves (lanes l and l^32 hold the same p)
        float4 o;
        o.x = __shfl_xor(t.x, 32); o.y = __shfl_xor(t.y, 32);
        o.z = __shfl_xor(t.z, 32); o.w = __shfl_xor(t.w, 32);
        ins4(t, o.x); ins4(t, o.y); ins4(t, o.z); ins4(t, o.w);
        o.x = __shfl_xor(u.x, 32); o.y = __shfl_xor(u.y, 32);
        o.z = __shfl_xor(u.z, 32); o.w = __shfl_xor(u.w, 32);
        ins4(u, o.x); ins4(u, o.y); ins4(u, o.z); ins4(u, o.w);
    }
    if (lh == 0) {
        const int gw = blockIdx.x * 4 + wid;
        cells[(long)gw * CD + l31]      = t;   // p = l31
        cells[(long)gw * CD + l31 + 32] = u;   // p = l31+32
    }
}

// k2: 64 blocks x 1024 thr, single launch. Block b: exact top-8 per p over
// its 48-row strip (per-thread top-8 of 12 values -> LDS merge -> sorted 8)
// -> cells2[b][p] -> fence+ticket; last block's wave 0 merges 64 sorted
// strips with early-break -> top-16 sum per p -> reduce -> out.
__global__ __launch_bounds__(1024) void k2_sel(
    const float4* __restrict__ cells, float* __restrict__ cells2,
    unsigned* __restrict__ ticket, float* __restrict__ out)
{
    const int b = blockIdx.x;
    const int tid = threadIdx.x;
    __shared__ float lmm[16][CD][9];   // 36 KB (pad 9 vs bank conflicts)
    __shared__ int islast;

    // per-thread top-8 over its 3 coalesced float4 (fixed p = tid&63)
    const float4* base = cells + (long)b * (STRIP * CD);
    float l8[8];
#pragma unroll
    for (int j = 0; j < 8; ++j) l8[j] = FMAXV;
    float cm = FMAXV;
#pragma unroll
    for (int q = 0; q < 3; ++q) {
        float4 v = base[q * 1024 + tid];
        SCREEN8(v.x, l8, cm); SCREEN8(v.y, l8, cm);
        SCREEN8(v.z, l8, cm); SCREEN8(v.w, l8, cm);
    }
    {
        const int rg = tid >> 6, p = tid & 63;
#pragma unroll
        for (int j = 0; j < 8; ++j) lmm[rg][p][j] = l8[j];
    }
    __syncthreads();

    if (tid < CD) {
        float m8[8];
#pragma unroll
        for (int j = 0; j < 8; ++j) m8[j] = FMAXV;
        float c8 = FMAXV;
#pragma unroll
        for (int g = 0; g < 16; ++g)
#pragma unroll
            for (int j = 0; j < 8; ++j) {
                float v = lmm[g][tid][j];
                SCREEN8(v, m8, c8);
            }
        // sort ascending (Batcher 8-net, 19 CSW)
        CSW(m8[0],m8[1]); CSW(m8[2],m8[3]); CSW(m8[4],m8[5]); CSW(m8[6],m8[7]);
        CSW(m8[0],m8[2]); CSW(m8[1],m8[3]); CSW(m8[4],m8[6]); CSW(m8[5],m8[7]);
        CSW(m8[1],m8[2]); CSW(m8[5],m8[6]);
        CSW(m8[0],m8[4]); CSW(m8[1],m8[5]); CSW(m8[2],m8[6]); CSW(m8[3],m8[7]);
        CSW(m8[2],m8[4]); CSW(m8[3],m8[5]);
        CSW(m8[1],m8[2]); CSW(m8[3],m8[4]); CSW(m8[5],m8[6]);
        float* c2 = cells2 + ((long)b * CD + tid) * 8;
#pragma unroll
        for (int j = 0; j < 8; ++j) c2[j] = m8[j];
        __threadfence();   // release this thread's cells2 writes
    }
    __syncthreads();
    if (tid == 0) islast = (atomicAdd(ticket, 1u) == CD - 1) ? 1 : 0;
    __syncthreads();

    if (islast && tid < CD) {
        __threadfence();   // acquire
        const int p = tid;
        float lst[16];
#pragma unroll
        for (int j = 0; j < 16; ++j) lst[j] = FMAXV;
        float cmx = FMAXV;
        for (int w = 0; w < CD; ++w) {
            const volatile float* c2 = cells2 + ((long)w * CD + p) * 8;
            float v = c2[0];
            if (!(v < cmx)) continue;          // sorted strip: all >= cmx
            SCREEN16(v, lst, cmx);
            for (int j = 1; j < 8; ++j) {
                v = c2[j];
                if (!(v < cmx)) break;
                SCREEN16(v, lst, cmx);
            }
        }
        float s = 0.f;
#pragma unroll
        for (int j = 0; j < 16; ++j) s += lst[j];
#pragma unroll
        for (int off = 32; off; off >>= 1) s += __shfl_xor(s, off);
        if (tid == 0) out[0] = -s / 1024.0f;
    }
}

extern "C" void kernel_launch(void* const* d_in, const int* in_sizes, int n_in,
                              void* d_out, int out_size, void* d_ws, size_t ws_size,
                              hipStream_t stream)
{
    const float* f1   = (const float*)d_in[0];
    const float* f2   = (const float*)d_in[1];
    const int*   nidx = (const int*)d_in[3];     // negative_indices
    float* out = (float*)d_out;

    float4*   cells  = (float4*)d_ws;                          // 3072*64*16 = 3 MB
    float*    cells2 = (float*)(cells + (long)K1_ROWS * CD);   // 64*64*8 fl = 128 KB
    unsigned* ticket = (unsigned*)(cells2 + (long)CD * CD * 8);

    k1_topk<<<K1_BLOCKS, 256, 0, stream>>>(f1, f2, nidx, cells, ticket);
    k2_sel <<<CD,       1024, 0, stream>>>(cells, cells2, ticket, out);
}

// Round 18
// 139.055 us; speedup vs baseline: 1.9103x; 1.9103x over previous
//
#include <hip/hip_runtime.h>
#include <cstdint>

#define CD 64
#define HWD 589824
#define K1_BLOCKS 1152
#define TPB 4                        // 128-col tiles per block (512-col span)
#define K1_ROWS (K1_BLOCKS * 4)      // 4608 cell rows (one per wave)
#define STRIP 72                     // cell rows per k2 strip-block
#define FMAXV 3.402823466e+38f

typedef float f32x16 __attribute__((ext_vector_type(16)));
typedef short bf16x8 __attribute__((ext_vector_type(8)));

__device__ __forceinline__ short f2bf(float f) {
    unsigned u = __float_as_uint(f);
    u = u + 0x7FFFu + ((u >> 16) & 1u);   // RNE
    return (short)(u >> 16);
}

// sorted top-4 insert: t.x <= t.y <= t.z <= t.w
__device__ __forceinline__ void ins4(float4& t, float x) {
    if (x < t.w) {
        if (x < t.z) { t.w = t.z;
            if (x < t.y) { t.z = t.y;
                if (x < t.x) { t.y = t.x; t.x = x; } else t.y = x;
            } else t.z = x;
        } else t.w = x;
    }
}

// unsorted 8-smallest screen (static indexing)
#define SCREEN8(d, lst, cm)                                                 \
    if ((d) < (cm)) {                                                       \
        bool rep = false;                                                   \
        _Pragma("unroll")                                                   \
        for (int j = 0; j < 8; ++j)                                         \
            if (!rep && lst[j] == (cm)) { lst[j] = (d); rep = true; }       \
        cm = lst[0];                                                        \
        _Pragma("unroll")                                                   \
        for (int j = 1; j < 8; ++j) cm = fmaxf(cm, lst[j]);                 \
    }

// unsorted 16-smallest screen (static indexing)
#define SCREEN16(d, lst, cm)                                                \
    if ((d) < (cm)) {                                                       \
        bool rep = false;                                                   \
        _Pragma("unroll")                                                   \
        for (int j = 0; j < 16; ++j)                                        \
            if (!rep && lst[j] == (cm)) { lst[j] = (d); rep = true; }       \
        cm = lst[0];                                                        \
        _Pragma("unroll")                                                   \
        for (int j = 1; j < 16; ++j) cm = fmaxf(cm, lst[j]);                \
    }

// kA: 64 blocks x 64 thr; thread k of block p loads one sel element.
__global__ __launch_bounds__(64) void kA_pack(
    const float* __restrict__ f1, const int* __restrict__ nidx,
    short* __restrict__ sel_bf, float* __restrict__ sel2,
    unsigned* __restrict__ ticket)
{
    const int p = blockIdx.x, k = threadIdx.x;
    if (p == 0 && k == 0) *ticket = 0u;
    float v = f1[(long)k * HWD + nidx[p]];
    float s = v * v;
#pragma unroll
    for (int off = 32; off; off >>= 1) s += __shfl_xor(s, off);
    sel_bf[p * CD + k] = f2bf(v);
    if (k == 0) sel2[p] = s;
}

// k1: R15-proven reg-staged async pipeline (plain float4 loads).
__global__ __launch_bounds__(256) void k1_topk(
    const float* __restrict__ f2, const short* __restrict__ sel_bf,
    const float* __restrict__ sel2, float4* __restrict__ cells)
{
    __shared__ float lds[CD][128];   // 32 KB
    const int tid = threadIdx.x;
    const int lane = tid & 63, wid = tid >> 6;
    const int l31 = lane & 31, lh = lane >> 5;
    const long nb = (long)blockIdx.x * (TPB * 128);

    const int srow = tid >> 5;          // 0..7
    const int scol = (tid & 31) * 4;    // float4 column

    bf16x8 sf0[4], sf1[4];
#pragma unroll
    for (int ks = 0; ks < 4; ++ks) {
        sf0[ks] = *(const bf16x8*)(sel_bf + l31 * CD + 16 * ks + 8 * lh);
        sf1[ks] = *(const bf16x8*)(sel_bf + (l31 + 32) * CD + 16 * ks + 8 * lh);
    }
    const float sel20 = sel2[l31], sel21 = sel2[l31 + 32];

    float4 st[8];
#pragma unroll
    for (int i = 0; i < 8; ++i)
        st[i] = *(const float4*)(f2 + (long)(8 * i + srow) * HWD + nb + scol);
    __builtin_amdgcn_sched_barrier(0);
#pragma unroll
    for (int i = 0; i < 8; ++i)
        *(float4*)&lds[8 * i + srow][scol] = st[i];

    float4 t = make_float4(FMAXV, FMAXV, FMAXV, FMAXV);
    float4 u = t;

#pragma unroll
    for (int tt = 0; tt < TPB; ++tt) {
        if (tt + 1 < TPB) {
#pragma unroll
            for (int i = 0; i < 8; ++i)
                st[i] = *(const float4*)(f2 + (long)(8 * i + srow) * HWD
                                         + nb + (long)(tt + 1) * 128 + scol);
            __builtin_amdgcn_sched_barrier(0);
        }
        asm volatile("s_waitcnt lgkmcnt(0)" ::: "memory");
        __builtin_amdgcn_sched_barrier(0);
        __builtin_amdgcn_s_barrier();
        __builtin_amdgcn_sched_barrier(0);

        const int col = wid * 32 + l31;
        float fs = 0.f;
        f32x16 a0, a1;
#pragma unroll
        for (int i = 0; i < 16; ++i) { a0[i] = 0.f; a1[i] = 0.f; }
#pragma unroll
        for (int ks = 0; ks < 4; ++ks) {
            bf16x8 af;
#pragma unroll
            for (int j = 0; j < 8; ++j) {
                float v = lds[16 * ks + 8 * lh + j][col];
                fs += v * v;
                af[j] = f2bf(v);
            }
            a0 = __builtin_amdgcn_mfma_f32_32x32x16_bf16(af, sf0[ks], a0, 0, 0, 0);
            a1 = __builtin_amdgcn_mfma_f32_32x32x16_bf16(af, sf1[ks], a1, 0, 0, 0);
        }
        fs += __shfl_xor(fs, 32);

#pragma unroll
        for (int i = 0; i < 16; ++i) {
            int r = (i & 3) + 8 * (i >> 2) + 4 * lh;
            float fr2 = __shfl(fs, r);
            ins4(t, fmaxf(sel20 + fr2 - 2.f * a0[i], 0.f));   // p = l31
            ins4(u, fmaxf(sel21 + fr2 - 2.f * a1[i], 0.f));   // p = l31+32
        }

        if (tt + 1 < TPB) {
            asm volatile("s_waitcnt lgkmcnt(0)" ::: "memory");
            __builtin_amdgcn_sched_barrier(0);
            __builtin_amdgcn_s_barrier();
            __builtin_amdgcn_sched_barrier(0);
#pragma unroll
            for (int i = 0; i < 8; ++i)
                *(float4*)&lds[8 * i + srow][scol] = st[i];
        }
    }

    {   // merge lh halves (lanes l and l^32 hold the same p)
        float4 o;
        o.x = __shfl_xor(t.x, 32); o.y = __shfl_xor(t.y, 32);
        o.z = __shfl_xor(t.z, 32); o.w = __shfl_xor(t.w, 32);
        ins4(t, o.x); ins4(t, o.y); ins4(t, o.z); ins4(t, o.w);
        o.x = __shfl_xor(u.x, 32); o.y = __shfl_xor(u.y, 32);
        o.z = __shfl_xor(u.z, 32); o.w = __shfl_xor(u.w, 32);
        ins4(u, o.x); ins4(u, o.y); ins4(u, o.z); ins4(u, o.w);
    }
    if (lh == 0) {
        const int gw = blockIdx.x * 4 + wid;
        cells[(long)gw * CD + l31]      = t;   // p = l31
        cells[(long)gw * CD + l31 + 32] = u;   // p = l31+32
    }
}

// k2: 64 blocks x 1024 thr, single launch.
// Strip phase: block b -> exact top-8 per p over its 72-row strip
// (per-thread top-8, coalesced reads, fixed p = tid&63) -> LDS merge ->
// cells2[p][b][8] (unsorted). Fence + ticket.
// Finish (last block only): 16 threads per p read cells2[p][*] in PARALLEL
// (32 independent volatile loads per thread) -> SCREEN16 -> width-16 shfl
// extraction of exact top-16 -> sum -> reduce -> out.
__global__ __launch_bounds__(1024) void k2_sel(
    const float4* __restrict__ cells, float* __restrict__ cells2,
    unsigned* __restrict__ ticket, float* __restrict__ out)
{
    const int b = blockIdx.x;
    const int tid = threadIdx.x;
    __shared__ float lmm[16][CD][9];   // 36 KB (pad 9: no bank conflict)
    __shared__ float psum[CD];
    __shared__ int islast;

    // strip phase: per-thread top-8 over 4-5 coalesced float4 (p = tid&63)
    const float4* base = cells + (long)b * (STRIP * CD);
    float l8[8];
#pragma unroll
    for (int j = 0; j < 8; ++j) l8[j] = FMAXV;
    float cm = FMAXV;
#pragma unroll
    for (int q = 0; q < 4; ++q) {               // 4*1024 of 4608
        float4 v = base[q * 1024 + tid];
        SCREEN8(v.x, l8, cm); SCREEN8(v.y, l8, cm);
        SCREEN8(v.z, l8, cm); SCREEN8(v.w, l8, cm);
    }
    if (tid < STRIP * CD - 4096) {              // tail 512
        float4 v = base[4096 + tid];
        SCREEN8(v.x, l8, cm); SCREEN8(v.y, l8, cm);
        SCREEN8(v.z, l8, cm); SCREEN8(v.w, l8, cm);
    }
    {
        const int rg = tid >> 6, p = tid & 63;
#pragma unroll
        for (int j = 0; j < 8; ++j) lmm[rg][p][j] = l8[j];
    }
    __syncthreads();

    if (tid < CD) {
        float m8[8];
#pragma unroll
        for (int j = 0; j < 8; ++j) m8[j] = FMAXV;
        float c8 = FMAXV;
#pragma unroll
        for (int g = 0; g < 16; ++g)
#pragma unroll
            for (int j = 0; j < 8; ++j) {
                float v = lmm[g][tid][j];
                SCREEN8(v, m8, c8);
            }
        float* c2 = cells2 + ((long)tid * CD + b) * 8;   // [p][strip][8]
#pragma unroll
        for (int j = 0; j < 8; ++j) c2[j] = m8[j];
    }
    __threadfence();
    __syncthreads();
    if (tid == 0) islast = (atomicAdd(ticket, 1u) == CD - 1) ? 1 : 0;
    __syncthreads();
    if (!islast) return;
    __threadfence();   // acquire

    // finish: 16 threads per p; thread g reads 32 contiguous-ish floats
    const int p = tid >> 4, g = tid & 15;
    const volatile float* src = cells2 + (long)p * CD * 8 + g * 32;
    float lst[16];
#pragma unroll
    for (int j = 0; j < 16; ++j) lst[j] = FMAXV;
    float cmx = FMAXV;
#pragma unroll
    for (int i = 0; i < 32; ++i) {
        float v = src[i];
        SCREEN16(v, lst, cmx);
    }

    // width-16 extraction: 16 rounds of subgroup-min (xor offsets < 16)
    float sum = 0.f;
    for (int rd = 0; rd < 16; ++rd) {
        float mn = lst[0]; int a = 0;
#pragma unroll
        for (int j = 1; j < 16; ++j) if (lst[j] < mn) { mn = lst[j]; a = j; }
        unsigned long long key =
            ((unsigned long long)__float_as_uint(mn) << 32) | (unsigned)(g * 16 + a);
#pragma unroll
        for (int off = 8; off; off >>= 1) {
            unsigned long long o = __shfl_xor(key, off);
            if (o < key) key = o;
        }
        sum += __uint_as_float((unsigned)(key >> 32));
        int slot = (int)(key & 0xFFFFFFFFu);
        if ((slot >> 4) == g) {
#pragma unroll
            for (int j = 0; j < 16; ++j) if (j == (slot & 15)) lst[j] = FMAXV;
        }
    }
    if (g == 0) psum[p] = sum;
    __syncthreads();
    if (tid < CD) {
        float s = psum[tid];
#pragma unroll
        for (int off = 32; off; off >>= 1) s += __shfl_xor(s, off);
        if (tid == 0) out[0] = -s / 1024.0f;
    }
}

extern "C" void kernel_launch(void* const* d_in, const int* in_sizes, int n_in,
                              void* d_out, int out_size, void* d_ws, size_t ws_size,
                              hipStream_t stream)
{
    const float* f1   = (const float*)d_in[0];
    const float* f2   = (const float*)d_in[1];
    const int*   nidx = (const int*)d_in[3];     // negative_indices
    float* out = (float*)d_out;

    float4*   cells  = (float4*)d_ws;                          // 4608*64*16 = 4.7 MB
    float*    cells2 = (float*)(cells + (long)K1_ROWS * CD);   // 64*64*8 fl = 128 KB
    short*    sel_bf = (short*)(cells2 + (long)CD * CD * 8);   // 8 KB
    float*    sel2   = (float*)(sel_bf + CD * CD);
    unsigned* ticket = (unsigned*)(sel2 + CD);

    kA_pack<<<CD,         64, 0, stream>>>(f1, nidx, sel_bf, sel2, ticket);
    k1_topk<<<K1_BLOCKS, 256, 0, stream>>>(f2, sel_bf, sel2, cells);
    k2_sel <<<CD,       1024, 0, stream>>>(cells, cells2, ticket, out);
}